// Round 2
// baseline (144.689 us; speedup 1.0000x reference)
//
#include <hip/hip_runtime.h>
#include <hip/hip_bf16.h>
#include <math.h>

#define NVARS 512
#define HID   16
#define TOPK  8

// ---------------- Kernel 1: routing (Q/K proj, sim, top-8, softmax) ----------
// Grid: 64 blocks x 512 threads. Wave w of block b handles row n = b*8 + w.
__global__ __launch_bounds__(512) void routing_kernel(
    const float* __restrict__ ve,   // (512,16)
    const float* __restrict__ Wq,   // (16,16)
    const float* __restrict__ bq,   // (16,)
    const float* __restrict__ Wk,   // (16,16)
    const float* __restrict__ bk,   // (16,)
    int*   __restrict__ out_idx,    // (512,8)
    float* __restrict__ out_w)      // (512,8)
{
    __shared__ float Ks[NVARS][HID + 1];   // stride 17 -> conflict-free

    const int t    = threadIdx.x;          // 0..511
    const int wave = t >> 6;               // 0..7
    const int lane = t & 63;
    const int n    = blockIdx.x * 8 + wave;  // row this wave owns

    // --- K[t][:] into LDS (each thread computes one K row) ---
    float vrow[HID];
    #pragma unroll
    for (int j = 0; j < HID; ++j) vrow[j] = ve[t * HID + j];
    #pragma unroll
    for (int h = 0; h < HID; ++h) {
        float s = bk[h];
        #pragma unroll
        for (int j = 0; j < HID; ++j) s += vrow[j] * Wk[h * HID + j];
        Ks[t][h] = s;
    }

    // --- Q[n][:] redundantly per lane (uniform loads, broadcast) ---
    float q[HID];
    #pragma unroll
    for (int j = 0; j < HID; ++j) vrow[j] = ve[n * HID + j];
    #pragma unroll
    for (int h = 0; h < HID; ++h) {
        float s = bq[h];
        #pragma unroll
        for (int j = 0; j < HID; ++j) s += vrow[j] * Wq[h * HID + j];
        q[h] = s;
    }

    __syncthreads();

    // --- sims for m = i*64 + lane (8 per lane = full 512 per wave) ---
    float vals[8];
    #pragma unroll
    for (int i = 0; i < 8; ++i) {
        const int m = i * 64 + lane;
        float s = 0.f;
        #pragma unroll
        for (int h = 0; h < HID; ++h) s += q[h] * Ks[m][h];
        vals[i] = (m == n) ? -1.0e9f : s;
    }

    // --- 8 rounds of wave-wide argmax (top-8) ---
    float mx = 0.f, my_val = 0.f, sum_exp = 0.f;
    int my_idx = 0;
    #pragma unroll
    for (int r = 0; r < TOPK; ++r) {
        float bv = vals[0];
        int   bi = lane;                    // m = 0*64 + lane
        #pragma unroll
        for (int i = 1; i < 8; ++i) {
            const int m = i * 64 + lane;
            if (vals[i] > bv) { bv = vals[i]; bi = m; }   // strict > keeps lowest m on tie
        }
        #pragma unroll
        for (int off = 32; off >= 1; off >>= 1) {
            const float ov = __shfl_xor(bv, off);
            const int   oi = __shfl_xor(bi, off);
            if (ov > bv || (ov == bv && oi < bi)) { bv = ov; bi = oi; }
        }
        // all lanes now hold round-r winner (bv, bi)
        if (r == 0) mx = bv;
        sum_exp += __expf(bv - mx);
        if (lane == r) { my_val = bv; my_idx = bi; }
        // owner lane retires the winner
        if ((bi & 63) == lane) {
            const int slot = bi >> 6;
            #pragma unroll
            for (int i = 0; i < 8; ++i)
                if (slot == i) vals[i] = -3.4e38f;
        }
    }

    if (lane < TOPK) {
        out_idx[n * TOPK + lane] = my_idx;
        out_w[n * TOPK + lane]   = __expf(my_val - mx) / sum_exp;
    }
}

// ---------------- Kernel 2: gather-weighted sum over rows --------------------
// R6: LDS bank-spread fix for the random gather.
// Post-mortem R5: removing the vmcnt(0) barrier drain was NEUTRAL (139.25 ->
// 139.19) => apply is NOT prefetch/barrier bound; 32 resident waves/CU
// already hide it. Revised theory: the gather layout was float4-slot at
// byte col*16 -> bank class = col mod 8 (only 8 classes). 64 lanes with
// random indices -> ~8-way avg / ~13 max bucket ~= 2.9x LDS serialization
// (m136), putting LDS (~25us) ABOVE the 21us HBM leg as apply's critical
// path (which is also why R5's barrier change was invisible).
// Fix: 40-byte stride per column (10 dwords: 8 data + 2 pad), gather via
// 4x float2 (ds_read_b64). Slot bank class = (10*col) mod 32 -> 16 classes
// (max possible for 8B-aligned reads) -> expected conflict ~1.5x.
// Writes gain a benign 4-way conflict (lanes 16 apart); writes are 1/9 of
// LDS traffic. LDS/block 32->40 KB: still 4 blocks/CU (32-wave cap binds).
// Barrier structure unchanged from R5 (1 lgkm-only barrier per 8-row group).
__global__ __launch_bounds__(512) void apply_kernel(
    const float* __restrict__ x,     // (32768, 512)
    const int*   __restrict__ gidx,  // (512, 8)
    const float* __restrict__ gw,    // (512, 8)
    float*       __restrict__ out)   // (32768, 512)
{
    // [buf][col*5 + k] : column col's 8 row-values in 4 float2 slots,
    // 40 B stride => bank class (10*col) mod 32, 16 classes.
    __shared__ float2 xs[2][NVARS * 5];   // 2 x 20 KB = 40 KB

    const int t = threadIdx.x;       // thread t owns column t (all rows)
    const int4   i0 = ((const int4*)gidx)[2 * t + 0];
    const int4   i1 = ((const int4*)gidx)[2 * t + 1];
    const float4 w0 = ((const float4*)gw)[2 * t + 0];
    const float4 w1 = ((const float4*)gw)[2 * t + 1];

    // hoisted float2-slot bases for the 8 gather columns (constant over groups)
    const int ix0 = i0.x * 5, ix1 = i0.y * 5, ix2 = i0.z * 5, ix3 = i0.w * 5;
    const int ix4 = i1.x * 5, ix5 = i1.y * 5, ix6 = i1.z * 5, ix7 = i1.w * 5;
    const int tb  = t * 5;

    const long base = (long)blockIdx.x * 32;

    // preload group 0: column t of rows base..base+7 (coalesced dword loads)
    const float* xp = x + base * NVARS + t;
    float v0 = xp[0 * NVARS];
    float v1 = xp[1 * NVARS];
    float v2 = xp[2 * NVARS];
    float v3 = xp[3 * NVARS];
    float v4 = xp[4 * NVARS];
    float v5 = xp[5 * NVARS];
    float v6 = xp[6 * NVARS];
    float v7 = xp[7 * NVARS];

    #pragma unroll 1
    for (int g = 0; g < 4; ++g) {
        float2* buf = xs[g & 1];
        buf[tb + 0] = make_float2(v0, v1);
        buf[tb + 1] = make_float2(v2, v3);
        buf[tb + 2] = make_float2(v4, v5);
        buf[tb + 3] = make_float2(v6, v7);

        // issue next group's prefetch BEFORE the barrier -- nothing drains
        // vmcnt at the barrier, so these flow across it.
        if (g < 3) {
            const float* xn = x + (base + 8 * (g + 1)) * NVARS + t;
            v0 = xn[0 * NVARS];
            v1 = xn[1 * NVARS];
            v2 = xn[2 * NVARS];
            v3 = xn[3 * NVARS];
            v4 = xn[4 * NVARS];
            v5 = xn[5 * NVARS];
            v6 = xn[6 * NVARS];
            v7 = xn[7 * NVARS];
        }

        // lgkm-only barrier: this group's ds_writes done + this wave's
        // gathers of group g-1 retired; do NOT drain vmcnt.
        asm volatile("s_waitcnt lgkmcnt(0)" ::: "memory");
        __builtin_amdgcn_s_barrier();
        asm volatile("" ::: "memory");   // no LDS op may hoist above barrier

        float a0 = 0.f, a1 = 0.f, a2 = 0.f, a3 = 0.f;
        float a4 = 0.f, a5 = 0.f, a6 = 0.f, a7 = 0.f;
        float2 p0, p1, p2, p3;
#define GATH(IX, WW)                                                     \
        p0 = buf[(IX) + 0]; p1 = buf[(IX) + 1];                          \
        p2 = buf[(IX) + 2]; p3 = buf[(IX) + 3];                          \
        a0 += p0.x * WW; a1 += p0.y * WW; a2 += p1.x * WW; a3 += p1.y * WW; \
        a4 += p2.x * WW; a5 += p2.y * WW; a6 += p3.x * WW; a7 += p3.y * WW;
        GATH(ix0, w0.x)
        GATH(ix1, w0.y)
        GATH(ix2, w0.z)
        GATH(ix3, w0.w)
        GATH(ix4, w1.x)
        GATH(ix5, w1.y)
        GATH(ix6, w1.z)
        GATH(ix7, w1.w)
#undef GATH

        float* o = out + (base + 8 * g) * NVARS + t;
        o[0 * NVARS] = a0;
        o[1 * NVARS] = a1;
        o[2 * NVARS] = a2;
        o[3 * NVARS] = a3;
        o[4 * NVARS] = a4;
        o[5 * NVARS] = a5;
        o[6 * NVARS] = a6;
        o[7 * NVARS] = a7;
        // no trailing barrier: next iteration's ds_writes target the other
        // buffer; same-buffer WAR is separated by the next barrier.
    }
}

extern "C" void kernel_launch(void* const* d_in, const int* in_sizes, int n_in,
                              void* d_out, int out_size, void* d_ws, size_t ws_size,
                              hipStream_t stream) {
    const float* x  = (const float*)d_in[0];   // (8,4096,512)
    const float* ve = (const float*)d_in[1];   // (512,16)
    const float* Wq = (const float*)d_in[2];   // (16,16)
    const float* bq = (const float*)d_in[3];   // (16,)
    const float* Wk = (const float*)d_in[4];   // (16,16)
    const float* bk = (const float*)d_in[5];   // (16,)
    float* out = (float*)d_out;

    int*   idx_ws = (int*)d_ws;
    float* w_ws   = (float*)((char*)d_ws + NVARS * TOPK * sizeof(int));

    routing_kernel<<<64, 512, 0, stream>>>(ve, Wq, bq, Wk, bk, idx_ws, w_ws);
    apply_kernel<<<1024, 512, 0, stream>>>(x, idx_ws, w_ws, out);
}